// Round 6
// baseline (1121.360 us; speedup 1.0000x reference)
//
#include <hip/hip_runtime.h>
#include <hip/hip_bf16.h>
#include <hip/hip_fp16.h>

// ---------------------------------------------------------------------------
// Attention (B=4, S=4096, d_model=d_attn=2048), fp32 in/out, bf16 MFMA.
// R5: 32x32x16 MFMA (half the MFMA issues, +15% pipe ceiling m119); R1's
//     race-free staging order (A->PAR^1 at ph0/ph1, B->PAR at ph2/ph3,
//     boundary vmcnt(4)); L2 supertile (4x4) block swizzle on top of the
//     XCD transform. Everything else as R3 (fused cast, fp16 logits,
//     in-place softmax, batched attention, named wrappers).
// A/B frag mapping 32x32x16: row=lane&31, k=(lane>>5)*8+j  [analogy of the
// verified 16x16x32 map]; C/D: col=lane&31, row=(reg&3)+8*(reg>>2)+
// 4*(lane>>5)  [verified m74/m101].
// Workspace: 416 MiB batched path (per-batch fallback at 320 MiB).
// ---------------------------------------------------------------------------

#define S_ 4096
#define DM_ 2048
#define DA_ 2048
#define NB_ 4

typedef __attribute__((ext_vector_type(8))) short short8;
typedef __attribute__((ext_vector_type(4))) float f32x4;
typedef __attribute__((ext_vector_type(16))) float f32x16;
typedef __attribute__((ext_vector_type(8))) unsigned short ushort8;

__device__ __forceinline__ void gload_lds16(const void* g, void* l) {
  __builtin_amdgcn_global_load_lds(
      (const __attribute__((address_space(1))) void*)g,
      (__attribute__((address_space(3))) void*)l, 16, 0, 0);
}

__device__ __forceinline__ unsigned short f2bf(float f) {
  __hip_bfloat16 h = __float2bfloat16(f);
  return __builtin_bit_cast(unsigned short, h);
}

// stage half-tiles (unchanged layout: [16r x 32c] subtile bricks, linear dst)
#define STAGE_A(par, h, kt)                                                    \
  {                                                                            \
    const __hip_bfloat16* s0 = Asrc + (size_t)((h)*128) * lda + (kt)*64;       \
    gload_lds16(s0, dstA + (par)*32768 + (h)*16384);                           \
    gload_lds16(s0 + (size_t)64 * lda, dstA + (par)*32768 + (h)*16384 + 8192); \
  }
#define STAGE_B(par, h, kt)                                                    \
  {                                                                            \
    const __hip_bfloat16* s0 = Bsrc + (size_t)((h)*128) * ldb + (kt)*64;       \
    gload_lds16(s0, dstB + (par)*32768 + (h)*16384);                           \
    gload_lds16(s0 + (size_t)64 * ldb, dstB + (par)*32768 + (h)*16384 + 8192); \
  }

// 32x32-fragment LDS reads (int offsets; ks&1 flips byte-bit5 = XOR swizzle)
#define LDA32(par, mi, ks)                                              \
  (*(const short8*)(lds + (par)*32768 +                                 \
                    ((aBase ^ (((ks)&1) << 5)) + (mi)*4096 + ((ks) >> 1) * 1024)))
#define LDB32(par, nj, ks)                                              \
  (*(const short8*)(lds + (par)*32768 +                                 \
                    ((bBase ^ (((ks)&1) << 5)) + (nj)*4096 + ((ks) >> 1) * 1024)))

#define MFMA_PHASE32(mi)                                                    \
  __builtin_amdgcn_s_setprio(1);                                            \
  _Pragma("unroll") for (int ks = 0; ks < 4; ++ks)                          \
      _Pragma("unroll") for (int nj = 0; nj < 2; ++nj)                      \
          acc[mi][nj] = __builtin_amdgcn_mfma_f32_32x32x16_bf16(            \
              A4[ks], Bf[nj][ks], acc[mi][nj], 0, 0, 0);                    \
  __builtin_amdgcn_s_setprio(0);                                            \
  __builtin_amdgcn_sched_barrier(0);

#define PHASE_SYNC_PRE                               \
  __builtin_amdgcn_sched_barrier(0);                 \
  __builtin_amdgcn_s_barrier();                      \
  asm volatile("s_waitcnt lgkmcnt(0)" ::: "memory"); \
  __builtin_amdgcn_sched_barrier(0);

// Per K-tile t (R1's race-free order):
//   ph0: read B(2nj x 4ks = 8) + A(mi0, 4); stage A.h0(t+1) -> PAR^1
//   ph1: read A(mi1);                       stage A.h1(t+1) -> PAR^1
//   ph2: read A(mi2);                       stage B.h0(t+2) -> PAR
//   ph3: read A(mi3);                       stage B.h1(t+2) -> PAR ; vmcnt(4)
// Boundary: queue=[B(t+1):4, A(t+1):4, B(t+2):4]; vmcnt(4) retires 8 ->
// tile t+1 fully staged, B(t+2) (4 loads) stays in flight.
// Race-free: A-DMA never targets PAR; B(PAR) re-written only after ph0's
// consumers retired (DMA issued >= 2 barriers later).
template <int PAR>
__device__ __forceinline__ void tile_body(
    int t, int NT, const __hip_bfloat16* __restrict__ Asrc,
    const __hip_bfloat16* __restrict__ Bsrc, int lda, int ldb, char* dstA,
    char* dstB, const char* lds, int aBase, int bBase, f32x16 (&acc)[4][2]) {
  const int tn = min(t + 1, NT - 1);
  const int tf = min(t + 2, NT - 1);
  short8 Bf[2][4], A4[4];

  // ph0
#pragma unroll
  for (int nj = 0; nj < 2; ++nj)
#pragma unroll
    for (int ks = 0; ks < 4; ++ks) Bf[nj][ks] = LDB32(PAR, nj, ks);
#pragma unroll
  for (int ks = 0; ks < 4; ++ks) A4[ks] = LDA32(PAR, 0, ks);
  STAGE_A(PAR ^ 1, 0, tn);
  PHASE_SYNC_PRE
  MFMA_PHASE32(0)
  __builtin_amdgcn_s_barrier();
  __builtin_amdgcn_sched_barrier(0);

  // ph1
#pragma unroll
  for (int ks = 0; ks < 4; ++ks) A4[ks] = LDA32(PAR, 1, ks);
  STAGE_A(PAR ^ 1, 1, tn);
  PHASE_SYNC_PRE
  MFMA_PHASE32(1)
  __builtin_amdgcn_s_barrier();
  __builtin_amdgcn_sched_barrier(0);

  // ph2
#pragma unroll
  for (int ks = 0; ks < 4; ++ks) A4[ks] = LDA32(PAR, 2, ks);
  STAGE_B(PAR, 0, tf);
  PHASE_SYNC_PRE
  MFMA_PHASE32(2)
  __builtin_amdgcn_s_barrier();
  __builtin_amdgcn_sched_barrier(0);

  // ph3
#pragma unroll
  for (int ks = 0; ks < 4; ++ks) A4[ks] = LDA32(PAR, 3, ks);
  STAGE_B(PAR, 1, tf);
  PHASE_SYNC_PRE
  MFMA_PHASE32(3)
  asm volatile("s_waitcnt vmcnt(4)" ::: "memory");
  __builtin_amdgcn_s_barrier();
  __builtin_amdgcn_sched_barrier(0);
}

// C[M,N] = A[M,K] * B[N,K]^T ; 256x256 tile, BK=64, 8 waves, 32x32x16 MFMA.
// EPI 0: C bf16 ; EPI 1: C fp16 * scale ; EPI 2: C fp32 + bias[col]
template <int EPI>
__device__ __forceinline__ void gemm8_body(
    const __hip_bfloat16* __restrict__ A, const __hip_bfloat16* __restrict__ Bm,
    void* __restrict__ Cv, const float* __restrict__ bias, int N, int K,
    int lda, int ldb, int ldc, float scale, long strideA, long strideB,
    long strideC) {
  __shared__ alignas(16) char lds[131072];
  const int tid = threadIdx.x;
  const int lane = tid & 63;
  const int w = tid >> 6;
  const int wr = w >> 2, wc = w & 3;

  // XCD-contiguous transform, then 4x4 supertile decode (L2 locality).
  const int nwg = (int)gridDim.x;
  int wg = (int)blockIdx.x;
  wg = (wg & 7) * (nwg >> 3) + (wg >> 3);
  const int nbn = N >> 8;
  const int nstx = nbn >> 2;
  const int st = wg >> 4;
  const int bm = (st / nstx) * 4 + ((wg >> 2) & 3);
  const int bn = (st % nstx) * 4 + (wg & 3);

  A += (long)blockIdx.y * strideA;
  Bm += (long)blockIdx.y * strideB;

  // staging source coords (pre-swizzled column; unchanged from R1-R3)
  const int R = ((w >> 1) << 4) + (lane >> 2);
  const int Cc = ((w & 1) << 5) + (((lane & 3) << 3) ^ ((lane & 32) >> 1));
  const __hip_bfloat16* Asrc = A + (size_t)(bm * 256 + R) * lda + Cc;
  const __hip_bfloat16* Bsrc = Bm + (size_t)(bn * 256 + R) * ldb + Cc;
  char* dstA = (char*)lds + w * 1024 + lane * 16;
  char* dstB = dstA + 65536;

  // 32x32-fragment read bases (byte offsets into lds)
  const int l5 = lane & 31;
  const int hi = lane >> 5;
  const int laneConst =
      (l5 >> 4) * 2048 + (l5 & 15) * 64 + hi * 16 + ((l5 & 8) << 2);
  const int aBase = wr * 16384 + laneConst;
  const int bBase = 65536 + (wc >> 1) * 16384 + (wc & 1) * 8192 + laneConst;

  const int NT = K >> 6;
  f32x16 acc[4][2] = {};

  // prologue: T0 all 4 halves -> par0 (8 loads); T1 B halves -> par1 (4);
  // vmcnt(4) retires T0, leaves B(1) in flight = steady state.
  STAGE_A(0, 0, 0)
  STAGE_A(0, 1, 0)
  STAGE_B(0, 0, 0)
  STAGE_B(0, 1, 0)
  STAGE_B(1, 0, 1)
  STAGE_B(1, 1, 1)
  asm volatile("s_waitcnt vmcnt(4)" ::: "memory");
  __builtin_amdgcn_s_barrier();
  __builtin_amdgcn_sched_barrier(0);

  for (int t = 0; t < NT; t += 2) {
    tile_body<0>(t, NT, Asrc, Bsrc, lda, ldb, dstA, dstB, (const char*)lds,
                 aBase, bBase, acc);
    tile_body<1>(t + 1, NT, Asrc, Bsrc, lda, ldb, dstA, dstB, (const char*)lds,
                 aBase, bBase, acc);
  }
  asm volatile("s_waitcnt vmcnt(0)" ::: "memory");

  // epilogue: 32x32 C/D layout col=lane&31, row=(reg&3)+8*(reg>>2)+4*hi
  float* Cf = (float*)Cv;
  __hip_bfloat16* Cb = (__hip_bfloat16*)Cv;
  __half* Ch = (__half*)Cv;
  const size_t cbase = (size_t)blockIdx.y * (size_t)strideC;
  const int r0 = bm * 256 + wr * 128 + (hi << 2);
  const int c0 = bn * 256 + wc * 64 + l5;
#pragma unroll
  for (int mi = 0; mi < 4; ++mi)
#pragma unroll
    for (int nj = 0; nj < 2; ++nj) {
      const int col = c0 + nj * 32;
#pragma unroll
      for (int reg = 0; reg < 16; ++reg) {
        const int row = r0 + mi * 32 + (reg & 3) + ((reg >> 2) << 3);
        const float v = acc[mi][nj][reg];
        if (EPI == 0)
          Cb[cbase + (size_t)row * ldc + col] = __float2bfloat16(v);
        else if (EPI == 1)
          Ch[cbase + (size_t)row * ldc + col] = __float2half(v * scale);
        else
          Cf[cbase + (size_t)row * ldc + col] = v + bias[col];
      }
    }
}

#define GEMM_WRAP(NAME, EPI)                                                   \
  __global__ __launch_bounds__(512, 1) void NAME(                             \
      const __hip_bfloat16* __restrict__ A,                                   \
      const __hip_bfloat16* __restrict__ Bm, void* __restrict__ Cv,           \
      const float* __restrict__ bias, int N, int K, int lda, int ldb,         \
      int ldc, float scale, long strideA, long strideB, long strideC) {       \
    gemm8_body<EPI>(A, Bm, Cv, bias, N, K, lda, ldb, ldc, scale, strideA,     \
                    strideB, strideC);                                        \
  }
GEMM_WRAP(g_qkproj, 0)
GEMM_WRAP(g_vt, 0)
GEMM_WRAP(g_qkt, 1)
GEMM_WRAP(g_pv, 0)
GEMM_WRAP(g_out, 2)

// one block per 4096-wide row: read fp16 logits, write bf16 probs IN PLACE
__global__ __launch_bounds__(256) void softmax_inplace(void* __restrict__ buf) {
  const int t = threadIdx.x;
  unsigned short* rp = (unsigned short*)buf + (size_t)blockIdx.x * S_;
  ushort8 h0 = ((const ushort8*)rp)[t * 2];
  ushort8 h1 = ((const ushort8*)rp)[t * 2 + 1];
  float v[16];
#pragma unroll
  for (int j = 0; j < 8; ++j) {
    v[j] = __half2float(__builtin_bit_cast(__half, (unsigned short)h0[j]));
    v[8 + j] = __half2float(__builtin_bit_cast(__half, (unsigned short)h1[j]));
  }
  float m = -1e30f;
#pragma unroll
  for (int j = 0; j < 16; ++j) m = fmaxf(m, v[j]);
#pragma unroll
  for (int off = 32; off > 0; off >>= 1) m = fmaxf(m, __shfl_xor(m, off));
  __shared__ float red[8];
  const int wv = t >> 6;
  if ((t & 63) == 0) red[wv] = m;
  __syncthreads();
  m = fmaxf(fmaxf(red[0], red[1]), fmaxf(red[2], red[3]));
  float e[16], s = 0.f;
#pragma unroll
  for (int j = 0; j < 16; ++j) {
    e[j] = __expf(v[j] - m);
    s += e[j];
  }
#pragma unroll
  for (int off = 32; off > 0; off >>= 1) s += __shfl_xor(s, off);
  if ((t & 63) == 0) red[4 + wv] = s;
  __syncthreads();
  s = (red[4] + red[5]) + (red[6] + red[7]);
  const float inv = 1.0f / s;
  ushort8 o0, o1;
#pragma unroll
  for (int j = 0; j < 8; ++j) {
    o0[j] = f2bf(e[j] * inv);
    o1[j] = f2bf(e[8 + j] * inv);
  }
  ((ushort8*)rp)[t * 2] = o0;
  ((ushort8*)rp)[t * 2 + 1] = o1;
}

// fused cast: x (16384 blocks) + Wq,Wk,Wv,Wo (2048 blocks each), 8 elems/thr
__global__ __launch_bounds__(256) void cast_all(
    const float* __restrict__ x, const float* __restrict__ wq,
    const float* __restrict__ wk, const float* __restrict__ wv,
    const float* __restrict__ wo, __hip_bfloat16* __restrict__ xb,
    __hip_bfloat16* __restrict__ wqkb, __hip_bfloat16* __restrict__ wvb,
    __hip_bfloat16* __restrict__ wob) {
  const int b = blockIdx.x;
  const float* src;
  __hip_bfloat16* dst;
  long base;
  if (b < 16384) {
    src = x; dst = xb; base = (long)b;
  } else if (b < 18432) {
    src = wq; dst = wqkb; base = (long)(b - 16384);
  } else if (b < 20480) {
    src = wk; dst = wqkb + (long)DA_ * DM_; base = (long)(b - 18432);
  } else if (b < 22528) {
    src = wv; dst = wvb; base = (long)(b - 20480);
  } else {
    src = wo; dst = wob; base = (long)(b - 22528);
  }
  const long i = (base * 256 + threadIdx.x) * 8;
  const f32x4 a = *(const f32x4*)(src + i);
  const f32x4 c = *(const f32x4*)(src + i + 4);
  ushort8 o;
#pragma unroll
  for (int j = 0; j < 4; ++j) o[j] = f2bf(a[j]);
#pragma unroll
  for (int j = 0; j < 4; ++j) o[4 + j] = f2bf(c[j]);
  *(ushort8*)(dst + i) = o;
}

extern "C" void kernel_launch(void* const* d_in, const int* in_sizes, int n_in,
                              void* d_out, int out_size, void* d_ws,
                              size_t ws_size, hipStream_t stream) {
  (void)in_sizes; (void)n_in; (void)out_size;
  const float* x = (const float*)d_in[0];
  const float* Wq = (const float*)d_in[1];
  const float* Wk = (const float*)d_in[2];
  const float* Wv = (const float*)d_in[3];
  const float* Wo = (const float*)d_in[4];
  const float* bo = (const float*)d_in[5];
  float* out = (float*)d_out;

  const long MB = 1ll << 20;
  char* ws = (char*)d_ws;
  __hip_bfloat16* Xb   = (__hip_bfloat16*)(ws);             // 64 MiB
  __hip_bfloat16* QKb  = (__hip_bfloat16*)(ws + 64 * MB);   // 128 MiB (Q|K)
  __hip_bfloat16* Vt   = (__hip_bfloat16*)(ws + 192 * MB);  // 64 MiB
  __hip_bfloat16* Wqkb = (__hip_bfloat16*)(ws + 256 * MB);  // 16 MiB
  __hip_bfloat16* Wvb  = (__hip_bfloat16*)(ws + 272 * MB);  // 8 MiB
  __hip_bfloat16* Wob  = (__hip_bfloat16*)(ws + 280 * MB);  // 8 MiB
  char* LgP            = ws + 288 * MB;  // 128 MiB batched / 32 MiB per-batch
  __hip_bfloat16* AO = Xb;  // x dead after projections; reuse

  const bool batched = ws_size >= (size_t)(416 * MB);

  cast_all<<<dim3(24576), dim3(256), 0, stream>>>(x, Wq, Wk, Wv, Wo, Xb, Wqkb,
                                                  Wvb, Wob);

  // fused Q|K projection: [16384, 4096] = Xb @ [Wq;Wk]^T
  g_qkproj<<<dim3(1024, 1), dim3(512), 0, stream>>>(
      Xb, Wqkb, QKb, nullptr, 4096, 2048, 2048, 2048, 4096, 1.f, 0, 0, 0);
  // Vt (batched): [2048, 4096] = Wv @ Xb_b^T
  g_vt<<<dim3(128, NB_), dim3(512), 0, stream>>>(
      Wvb, Xb, Vt, nullptr, 4096, 2048, 2048, 2048, 4096, 1.f, 0,
      (long)S_ * DM_, (long)DA_ * S_);

  const float scale = 0.022097086912079608f;  // 1/sqrt(d_model=2048)
  if (batched) {
    g_qkt<<<dim3(256, NB_), dim3(512), 0, stream>>>(
        QKb, QKb + DA_, LgP, nullptr, 4096, 2048, 4096, 4096, 4096, scale,
        (long)S_ * 2 * DA_, (long)S_ * 2 * DA_, (long)S_ * S_);
    softmax_inplace<<<dim3(NB_ * S_), dim3(256), 0, stream>>>(LgP);
    g_pv<<<dim3(128, NB_), dim3(512), 0, stream>>>(
        (const __hip_bfloat16*)LgP, Vt, AO, nullptr, 2048, 4096, 4096, 4096,
        2048, 1.f, (long)S_ * S_, (long)DA_ * S_, (long)S_ * DA_);
  } else {
    for (int b = 0; b < NB_; ++b) {
      const __hip_bfloat16* Qb = QKb + (size_t)b * S_ * 2 * DA_;
      g_qkt<<<dim3(256, 1), dim3(512), 0, stream>>>(
          Qb, Qb + DA_, LgP, nullptr, 4096, 2048, 4096, 4096, 4096, scale, 0,
          0, 0);
      softmax_inplace<<<dim3(S_), dim3(256), 0, stream>>>(LgP);
      g_pv<<<dim3(128, 1), dim3(512), 0, stream>>>(
          (const __hip_bfloat16*)LgP, Vt + (size_t)b * DA_ * S_,
          AO + (size_t)b * S_ * DA_, nullptr, 2048, 4096, 4096, 4096, 2048,
          1.f, 0, 0, 0);
    }
  }
  // out = AO @ Wo^T + bo (fp32)
  g_out<<<dim3(512, 1), dim3(512), 0, stream>>>(
      AO, Wob, out, bo, 2048, 2048, 2048, 2048, 2048, 1.f, 0, 0, 0);
}

// Round 7
// 834.164 us; speedup vs baseline: 1.3443x; 1.3443x over previous
//
#include <hip/hip_runtime.h>
#include <hip/hip_bf16.h>
#include <hip/hip_fp16.h>

// ---------------------------------------------------------------------------
// Attention (B=4, S=4096, d_model=d_attn=2048), fp32 in/out, bf16 MFMA.
// R6: algebraic refactor -- Q,K,V,out-proj eliminated:
//   Gt  = Wk^T-row-major GEMM pair:  Gt = bt(WkT, WqT)   (G = Wq^T Wk)
//   Wvo = bt(Wo, WvT)                (Wvo = Wo Wv)        [y=2 fused dispatch]
//   xG  = bt(Xb, Gt)        [16384,2048] 137 GF
//   VOt = bt(Wvo, Xb_b)     [2048,4096]x4 137 GF
//   Lg  = bt(xG_b, Xb_b)*scale -> fp16 [4096,4096]x4 275 GF
//   P   = softmax(Lg) in place (bf16)
//   out = bt(P_b, VOt_b) + bo -> fp32  275 GF
// Total 858 GF (was 1100). GEMM core = R1 structure (best measured: 226us,
// MfmaUtil 53, 0 bank conflicts) + R5's 4x4 supertile L2 decode (FETCH -33%).
// Workspace: 368 MiB.
// ---------------------------------------------------------------------------

#define S_ 4096
#define DM_ 2048
#define DA_ 2048
#define NB_ 4

typedef __attribute__((ext_vector_type(8))) short short8;
typedef __attribute__((ext_vector_type(4))) float f32x4;
typedef __attribute__((ext_vector_type(8))) unsigned short ushort8;

__device__ __forceinline__ void gload_lds16(const void* g, void* l) {
  __builtin_amdgcn_global_load_lds(
      (const __attribute__((address_space(1))) void*)g,
      (__attribute__((address_space(3))) void*)l, 16, 0, 0);
}

__device__ __forceinline__ unsigned short f2bf(float f) {
  __hip_bfloat16 h = __float2bfloat16(f);
  return __builtin_bit_cast(unsigned short, h);
}

#define STAGE_A(par, h, kt)                                                    \
  {                                                                            \
    const __hip_bfloat16* s0 = Asrc + (size_t)((h)*128) * lda + (kt)*64;       \
    gload_lds16(s0, dstA + (par)*32768 + (h)*16384);                           \
    gload_lds16(s0 + (size_t)64 * lda, dstA + (par)*32768 + (h)*16384 + 8192); \
  }
#define STAGE_B(par, h, kt)                                                    \
  {                                                                            \
    const __hip_bfloat16* s0 = Bsrc + (size_t)((h)*128) * ldb + (kt)*64;       \
    gload_lds16(s0, dstB + (par)*32768 + (h)*16384);                           \
    gload_lds16(s0 + (size_t)64 * ldb, dstB + (par)*32768 + (h)*16384 + 8192); \
  }
#define LDA_FRAG(par, mi, i, kk) \
  (*(const short8*)(ldsAr + (par)*32768 + ((mi)*2 + (i)) * 2048 + (kk)*1024))
#define LDB_FRAG(par, j, kk) \
  (*(const short8*)(ldsBr + (par)*32768 + (j)*2048 + (kk)*1024))

#define MFMA_PHASE(mi)                                                      \
  __builtin_amdgcn_s_setprio(1);                                            \
  _Pragma("unroll") for (int i = 0; i < 2; ++i)                             \
      _Pragma("unroll") for (int j = 0; j < 4; ++j)                         \
          _Pragma("unroll") for (int kk = 0; kk < 2; ++kk)                  \
              acc[(mi)*2 + i][j] = __builtin_amdgcn_mfma_f32_16x16x32_bf16( \
                  Af[i][kk], Bf[j][kk], acc[(mi)*2 + i][j], 0, 0, 0);       \
  __builtin_amdgcn_s_setprio(0);                                            \
  __builtin_amdgcn_sched_barrier(0);

#define PHASE_SYNC_PRE                               \
  __builtin_amdgcn_sched_barrier(0);                 \
  __builtin_amdgcn_s_barrier();                      \
  asm volatile("s_waitcnt lgkmcnt(0)" ::: "memory"); \
  __builtin_amdgcn_sched_barrier(0);

// R1's race-free schedule: A-DMA targets PAR^1 only (never the parity being
// read); B[PAR]-DMA issues >=2 barriers after B[PAR]'s readers retired.
//   ph0: read B(8)+A(mi0); stage A.h0(t+1)->PAR^1
//   ph1: read A(mi1);      stage A.h1(t+1)->PAR^1
//   ph2: read A(mi2);      stage B.h0(t+2)->PAR
//   ph3: read A(mi3);      stage B.h1(t+2)->PAR ; vmcnt(4)
// FIFO at boundary: [B(t+1):4, A(t+1):4, B(t+2):4] -> vmcnt(4) retires 8:
// tile t+1 fully staged; B(t+2) (4 loads) in flight. Tail clamps idempotent.
template <int PAR>
__device__ __forceinline__ void tile_body(
    int t, int NT, const __hip_bfloat16* __restrict__ Asrc,
    const __hip_bfloat16* __restrict__ Bsrc, int lda, int ldb, char* dstA,
    char* dstB, const char* ldsAr, const char* ldsBr, f32x4 (&acc)[8][4]) {
  const int tn = min(t + 1, NT - 1);
  const int tf = min(t + 2, NT - 1);
  short8 Bf[4][2], Af[2][2];

  // ph0
#pragma unroll
  for (int j = 0; j < 4; ++j)
#pragma unroll
    for (int kk = 0; kk < 2; ++kk) Bf[j][kk] = LDB_FRAG(PAR, j, kk);
#pragma unroll
  for (int i = 0; i < 2; ++i)
#pragma unroll
    for (int kk = 0; kk < 2; ++kk) Af[i][kk] = LDA_FRAG(PAR, 0, i, kk);
  STAGE_A(PAR ^ 1, 0, tn);
  PHASE_SYNC_PRE
  MFMA_PHASE(0)
  __builtin_amdgcn_s_barrier();
  __builtin_amdgcn_sched_barrier(0);

  // ph1
#pragma unroll
  for (int i = 0; i < 2; ++i)
#pragma unroll
    for (int kk = 0; kk < 2; ++kk) Af[i][kk] = LDA_FRAG(PAR, 1, i, kk);
  STAGE_A(PAR ^ 1, 1, tn);
  PHASE_SYNC_PRE
  MFMA_PHASE(1)
  __builtin_amdgcn_s_barrier();
  __builtin_amdgcn_sched_barrier(0);

  // ph2
#pragma unroll
  for (int i = 0; i < 2; ++i)
#pragma unroll
    for (int kk = 0; kk < 2; ++kk) Af[i][kk] = LDA_FRAG(PAR, 2, i, kk);
  STAGE_B(PAR, 0, tf);
  PHASE_SYNC_PRE
  MFMA_PHASE(2)
  __builtin_amdgcn_s_barrier();
  __builtin_amdgcn_sched_barrier(0);

  // ph3
#pragma unroll
  for (int i = 0; i < 2; ++i)
#pragma unroll
    for (int kk = 0; kk < 2; ++kk) Af[i][kk] = LDA_FRAG(PAR, 3, i, kk);
  STAGE_B(PAR, 1, tf);
  PHASE_SYNC_PRE
  MFMA_PHASE(3)
  asm volatile("s_waitcnt vmcnt(4)" ::: "memory");
  __builtin_amdgcn_s_barrier();
  __builtin_amdgcn_sched_barrier(0);
}

// C[M,N] = A[M,K] * B[N,K]^T ; 256x256 tile, BK=64, 8 waves, 16x16x32 MFMA.
// EPI 0: C bf16 ; EPI 1: C fp16 * scale ; EPI 2: C fp32 + bias[col]
template <int EPI>
__device__ __forceinline__ void gemm8_body(
    const __hip_bfloat16* __restrict__ A, const __hip_bfloat16* __restrict__ Bm,
    void* __restrict__ Cv, const float* __restrict__ bias, int N, int K,
    int lda, int ldb, int ldc, float scale, long strideA, long strideB,
    long strideC) {
  __shared__ alignas(16) char lds[131072];
  const int tid = threadIdx.x;
  const int lane = tid & 63;
  const int w = tid >> 6;
  const int wr = w >> 2, wc = w & 3;

  // XCD-contiguous transform, then 4x4 supertile decode (L2 locality).
  // Requires grid.x % 8 == 0, nbm % 4 == 0, nbn % 4 == 0 (all call sites ok).
  const int nwg = (int)gridDim.x;
  int wg = (int)blockIdx.x;
  wg = (wg & 7) * (nwg >> 3) + (wg >> 3);
  const int nbn = N >> 8;
  const int nstx = nbn >> 2;
  const int st = wg >> 4;
  const int bm = (st / nstx) * 4 + ((wg >> 2) & 3);
  const int bn = (st % nstx) * 4 + (wg & 3);

  A += (long)blockIdx.y * strideA;
  Bm += (long)blockIdx.y * strideB;

  // staging source coords (pre-swizzled column: involution of read XOR)
  const int R = ((w >> 1) << 4) + (lane >> 2);
  const int Cc = ((w & 1) << 5) + (((lane & 3) << 3) ^ ((lane & 32) >> 1));
  const __hip_bfloat16* Asrc = A + (size_t)(bm * 256 + R) * lda + Cc;
  const __hip_bfloat16* Bsrc = Bm + (size_t)(bn * 256 + R) * ldb + Cc;
  char* dstA = lds + w * 1024 + lane * 16;
  char* dstB = dstA + 65536;

  // read-side swizzled base offsets (verified conflict-free, R1-R3)
  const int fr = lane & 15;
  const int fk2 = (lane >> 4) << 4;
  const int rby = fr * 64 + (fk2 ^ ((fr & 8) << 2));
  const char* ldsAr = lds + wr * 16384 + rby;
  const char* ldsBr = lds + 65536 + (wc >> 1) * 16384 + (wc & 1) * 8192 + rby;

  const int NT = K >> 6;
  f32x4 acc[8][4] = {};

  // prologue: T0 all 4 halves -> par0; T1 B halves -> par1; vmcnt(4) keeps
  // T1's B (4 loads) in flight = steady state.
  STAGE_A(0, 0, 0)
  STAGE_A(0, 1, 0)
  STAGE_B(0, 0, 0)
  STAGE_B(0, 1, 0)
  STAGE_B(1, 0, 1)
  STAGE_B(1, 1, 1)
  asm volatile("s_waitcnt vmcnt(4)" ::: "memory");
  __builtin_amdgcn_s_barrier();
  __builtin_amdgcn_sched_barrier(0);

  for (int t = 0; t < NT; t += 2) {
    tile_body<0>(t, NT, Asrc, Bsrc, lda, ldb, dstA, dstB, ldsAr, ldsBr, acc);
    tile_body<1>(t + 1, NT, Asrc, Bsrc, lda, ldb, dstA, dstB, ldsAr, ldsBr,
                 acc);
  }
  asm volatile("s_waitcnt vmcnt(0)" ::: "memory");

  // epilogue: C/D layout col=lane&15, row=(lane>>4)*4+reg  [verified m89/m91]
  float* Cf = (float*)Cv;
  __hip_bfloat16* Cb = (__hip_bfloat16*)Cv;
  __half* Ch = (__half*)Cv;
  const size_t cbase = (size_t)blockIdx.y * (size_t)strideC;
  const int r0 = bm * 256 + wr * 128 + ((lane >> 4) << 2);
  const int c0 = bn * 256 + wc * 64 + fr;
#pragma unroll
  for (int mi = 0; mi < 4; ++mi)
#pragma unroll
    for (int i = 0; i < 2; ++i)
#pragma unroll
      for (int j = 0; j < 4; ++j) {
        const int row = r0 + mi * 32 + i * 16;
        const int col = c0 + j * 16;
#pragma unroll
        for (int r = 0; r < 4; ++r) {
          const float v = acc[mi * 2 + i][j][r];
          if (EPI == 0)
            Cb[cbase + (size_t)(row + r) * ldc + col] = __float2bfloat16(v);
          else if (EPI == 1)
            Ch[cbase + (size_t)(row + r) * ldc + col] = __float2half(v * scale);
          else
            Cf[cbase + (size_t)(row + r) * ldc + col] = v + bias[col];
        }
      }
}

#define GEMM_WRAP(NAME, EPI)                                                   \
  __global__ __launch_bounds__(512, 1) void NAME(                              \
      const __hip_bfloat16* __restrict__ A,                                    \
      const __hip_bfloat16* __restrict__ Bm, void* __restrict__ Cv,            \
      const float* __restrict__ bias, int N, int K, int lda, int ldb,          \
      int ldc, float scale, long strideA, long strideB, long strideC) {        \
    gemm8_body<EPI>(A, Bm, Cv, bias, N, K, lda, ldb, ldc, scale, strideA,      \
                    strideB, strideC);                                         \
  }
GEMM_WRAP(g_small, 0)   // y=2: {Gt, Wvo} 2048^3 pair
GEMM_WRAP(g_xg, 0)      // xG = Xb @ Gt^T
GEMM_WRAP(g_vot, 0)     // VOt_b = Wvo @ Xb_b^T
GEMM_WRAP(g_qkt, 1)     // Lg_b = xG_b @ Xb_b^T * scale (fp16)
GEMM_WRAP(g_pv, 2)      // out_b = P_b @ VOt_b^T + bo (fp32)

// one block per 4096-wide row: read fp16 logits, write bf16 probs IN PLACE
__global__ __launch_bounds__(256) void softmax_inplace(void* __restrict__ buf) {
  const int t = threadIdx.x;
  unsigned short* rp = (unsigned short*)buf + (size_t)blockIdx.x * S_;
  ushort8 h0 = ((const ushort8*)rp)[t * 2];
  ushort8 h1 = ((const ushort8*)rp)[t * 2 + 1];
  float v[16];
#pragma unroll
  for (int j = 0; j < 8; ++j) {
    v[j] = __half2float(__builtin_bit_cast(__half, (unsigned short)h0[j]));
    v[8 + j] = __half2float(__builtin_bit_cast(__half, (unsigned short)h1[j]));
  }
  float m = -1e30f;
#pragma unroll
  for (int j = 0; j < 16; ++j) m = fmaxf(m, v[j]);
#pragma unroll
  for (int off = 32; off > 0; off >>= 1) m = fmaxf(m, __shfl_xor(m, off));
  __shared__ float red[8];
  const int wv = t >> 6;
  if ((t & 63) == 0) red[wv] = m;
  __syncthreads();
  m = fmaxf(fmaxf(red[0], red[1]), fmaxf(red[2], red[3]));
  float e[16], s = 0.f;
#pragma unroll
  for (int j = 0; j < 16; ++j) {
    e[j] = __expf(v[j] - m);
    s += e[j];
  }
#pragma unroll
  for (int off = 32; off > 0; off >>= 1) s += __shfl_xor(s, off);
  if ((t & 63) == 0) red[4 + wv] = s;
  __syncthreads();
  s = (red[4] + red[5]) + (red[6] + red[7]);
  const float inv = 1.0f / s;
  ushort8 o0, o1;
#pragma unroll
  for (int j = 0; j < 8; ++j) {
    o0[j] = f2bf(e[j] * inv);
    o1[j] = f2bf(e[8 + j] * inv);
  }
  ((ushort8*)rp)[t * 2] = o0;
  ((ushort8*)rp)[t * 2 + 1] = o1;
}

// transpose-cast one 64x64 tile of a 2048x2048 f32 matrix -> bf16 transposed
__device__ __forceinline__ void tcast64(const float* __restrict__ src,
                                        __hip_bfloat16* __restrict__ dst,
                                        int tile) {
  __shared__ __hip_bfloat16 lt[64][65];
  const int ti = tile >> 5;
  const int tj = tile & 31;
  const int t = threadIdx.x;
  const int r = t >> 4;
  const int c4 = (t & 15) * 4;
#pragma unroll
  for (int rr = 0; rr < 4; ++rr) {
    const int row = ti * 64 + rr * 16 + r;
    const f32x4 v = *(const f32x4*)(src + (size_t)row * 2048 + tj * 64 + c4);
#pragma unroll
    for (int k = 0; k < 4; ++k)
      lt[c4 + k][rr * 16 + r] = __float2bfloat16(v[k]);
  }
  __syncthreads();
  const int a = t >> 2;
  const int b16 = (t & 3) * 16;
  ushort8* dp = (ushort8*)(dst + (size_t)(tj * 64 + a) * 2048 + ti * 64 + b16);
  const unsigned short* lp = (const unsigned short*)&lt[a][b16];
  ushort8 o0, o1;
#pragma unroll
  for (int k = 0; k < 8; ++k) {
    o0[k] = lp[k];
    o1[k] = lp[8 + k];
  }
  dp[0] = o0;
  dp[1] = o1;
}

// fused cast: x plain (16384), Wo plain (2048), Wq/Wk/Wv transpose (1024 ea)
__global__ __launch_bounds__(256) void cast_all(
    const float* __restrict__ x, const float* __restrict__ wq,
    const float* __restrict__ wk, const float* __restrict__ wv,
    const float* __restrict__ wo, __hip_bfloat16* __restrict__ xb,
    __hip_bfloat16* __restrict__ wqt, __hip_bfloat16* __restrict__ wkt,
    __hip_bfloat16* __restrict__ wvt, __hip_bfloat16* __restrict__ wob) {
  const int b = blockIdx.x;
  if (b >= 18432) {
    if (b < 19456) tcast64(wq, wqt, b - 18432);
    else if (b < 20480) tcast64(wk, wkt, b - 19456);
    else tcast64(wv, wvt, b - 20480);
    return;
  }
  const float* src;
  __hip_bfloat16* dst;
  long base;
  if (b < 16384) {
    src = x; dst = xb; base = (long)b;
  } else {
    src = wo; dst = wob; base = (long)(b - 16384);
  }
  const long i = (base * 256 + threadIdx.x) * 8;
  const f32x4 a = *(const f32x4*)(src + i);
  const f32x4 c = *(const f32x4*)(src + i + 4);
  ushort8 o;
#pragma unroll
  for (int j = 0; j < 4; ++j) o[j] = f2bf(a[j]);
#pragma unroll
  for (int j = 0; j < 4; ++j) o[4 + j] = f2bf(c[j]);
  *(ushort8*)(dst + i) = o;
}

extern "C" void kernel_launch(void* const* d_in, const int* in_sizes, int n_in,
                              void* d_out, int out_size, void* d_ws,
                              size_t ws_size, hipStream_t stream) {
  (void)in_sizes; (void)n_in; (void)out_size; (void)ws_size;
  const float* x = (const float*)d_in[0];
  const float* Wq = (const float*)d_in[1];
  const float* Wk = (const float*)d_in[2];
  const float* Wv = (const float*)d_in[3];
  const float* Wo = (const float*)d_in[4];
  const float* bo = (const float*)d_in[5];
  float* out = (float*)d_out;

  const long MB = 1ll << 20;
  char* ws = (char*)d_ws;  // 368 MiB
  __hip_bfloat16* Xb  = (__hip_bfloat16*)(ws);             // 64 MiB
  __hip_bfloat16* xG  = (__hip_bfloat16*)(ws + 64 * MB);   // 64 MiB
  __hip_bfloat16* VOt = (__hip_bfloat16*)(ws + 128 * MB);  // 64 MiB
  __hip_bfloat16* WkT = (__hip_bfloat16*)(ws + 192 * MB);  // 8 MiB  [smallA y0]
  __hip_bfloat16* Wob = (__hip_bfloat16*)(ws + 200 * MB);  // 8 MiB  [smallA y1]
  __hip_bfloat16* WqT = (__hip_bfloat16*)(ws + 208 * MB);  // 8 MiB  [smallB y0]
  __hip_bfloat16* WvT = (__hip_bfloat16*)(ws + 216 * MB);  // 8 MiB  [smallB y1]
  __hip_bfloat16* Gt  = (__hip_bfloat16*)(ws + 224 * MB);  // 8 MiB  [smallC y0]
  __hip_bfloat16* Wvo = (__hip_bfloat16*)(ws + 232 * MB);  // 8 MiB  [smallC y1]
  char* LgP           = ws + 240 * MB;                     // 128 MiB

  const long WSTRIDE = 8 * MB / 2;  // elements between y=0 / y=1 operands

  cast_all<<<dim3(21504), dim3(256), 0, stream>>>(x, Wq, Wk, Wv, Wo, Xb, WqT,
                                                  WkT, WvT, Wob);

  // {Gt, Wvo} = { bt(WkT,WqT), bt(Wob,WvT) } : one y=2 dispatch, 2048^3 each
  g_small<<<dim3(64, 2), dim3(512), 0, stream>>>(
      WkT, WqT, Gt, nullptr, 2048, 2048, 2048, 2048, 2048, 1.f, WSTRIDE,
      WSTRIDE, WSTRIDE);
  // xG = bt(Xb, Gt): [16384, 2048], K=2048
  g_xg<<<dim3(512, 1), dim3(512), 0, stream>>>(
      Xb, Gt, xG, nullptr, 2048, 2048, 2048, 2048, 2048, 1.f, 0, 0, 0);
  // VOt_b = bt(Wvo, Xb_b): [2048, 4096] x4, K=2048
  g_vot<<<dim3(128, NB_), dim3(512), 0, stream>>>(
      Wvo, Xb, VOt, nullptr, 4096, 2048, 2048, 2048, 4096, 1.f, 0,
      (long)S_ * DM_, (long)DA_ * S_);

  const float scale = 0.022097086912079608f;  // 1/sqrt(d_model=2048)
  // Lg_b = bt(xG_b, Xb_b)*scale -> fp16 [4096,4096] x4, K=2048
  g_qkt<<<dim3(256, NB_), dim3(512), 0, stream>>>(
      xG, Xb, LgP, nullptr, 4096, 2048, 2048, 2048, 4096, scale,
      (long)S_ * DA_, (long)S_ * DM_, (long)S_ * S_);
  softmax_inplace<<<dim3(NB_ * S_), dim3(256), 0, stream>>>(LgP);
  // out_b = bt(P_b, VOt_b) + bo -> fp32 [4096, 2048] x4, K=4096
  g_pv<<<dim3(128, NB_), dim3(512), 0, stream>>>(
      (const __hip_bfloat16*)LgP, VOt, out, bo, 2048, 4096, 4096, 4096, 2048,
      1.f, (long)S_ * S_, (long)DA_ * S_, (long)S_ * DM_);
}